// Round 1
// baseline (290.843 us; speedup 1.0000x reference)
//
#include <hip/hip_runtime.h>
#include <hip/hip_bf16.h>
#include <cstdint>

#define D_MODEL 1024
#define NHEAD 16
#define DKH 64
#define BATCH 4
#define SEQ 2048
#define M_TOT (BATCH*SEQ)   // 8192

typedef __bf16 bf16;
typedef __bf16 bf16x8 __attribute__((ext_vector_type(8)));
typedef __bf16 bf16x4 __attribute__((ext_vector_type(4)));
typedef float  f32x4  __attribute__((ext_vector_type(4)));
typedef float  f32x16 __attribute__((ext_vector_type(16)));

// async global->LDS, 16B per lane. LDS dest must be wave-uniform base; HW adds lane*16.
__device__ __forceinline__ void async_ld16(const void* g, void* l) {
    __builtin_amdgcn_global_load_lds(
        (__attribute__((address_space(1))) void*)(uintptr_t)g,
        (__attribute__((address_space(3))) void*)(uintptr_t)l,
        16, 0, 0);
}

__device__ __forceinline__ unsigned pack2_bf16(float lo, float hi) {
    union { __bf16 h[2]; unsigned u; } w;
    w.h[0] = (bf16)lo; w.h[1] = (bf16)hi;
    return w.u;   // low 16 = lo (even key), high 16 = hi
}

// ---------------- merged convert: x fp32->bf16 (blocks 0..8191) and
// weight convert+transpose W[K][N] fp32 -> Wt[N][K] bf16 (blocks 8192..12287) ----------------
__global__ __launch_bounds__(256) void k_cvt(const float* __restrict__ x,
                                             bf16* __restrict__ xb,
                                             const float* __restrict__ wq,
                                             const float* __restrict__ wk,
                                             const float* __restrict__ wv,
                                             const float* __restrict__ wo,
                                             bf16* __restrict__ wt) {
    __shared__ float t[32][33];
    int bid = blockIdx.x;
    if (bid < 8192) {
        int i = (bid * 256 + threadIdx.x) * 4;
        float4 f = *(const float4*)(x + i);
        bf16x4 o;
        o[0] = (bf16)f.x; o[1] = (bf16)f.y; o[2] = (bf16)f.z; o[3] = (bf16)f.w;
        *(bf16x4*)(xb + i) = o;
    } else {
        int wb = bid - 8192;                  // 0..4095
        int z = wb >> 10;
        int rem = wb & 1023;
        const float* W = (z == 0) ? wq : (z == 1) ? wk : (z == 2) ? wv : wo;
        bf16* T = wt + (size_t)z * D_MODEL * D_MODEL;
        int tx = threadIdx.x & 31, ty = threadIdx.x >> 5;   // (32,8)
        int bx = (rem & 31) * 32, by = (rem >> 5) * 32;
#pragma unroll
        for (int i = 0; i < 4; i++)
            t[ty + i * 8][tx] = W[(size_t)(by + ty + i * 8) * D_MODEL + bx + tx];
        __syncthreads();
#pragma unroll
        for (int i = 0; i < 4; i++)
            T[(size_t)(bx + ty + i * 8) * D_MODEL + by + tx] = (bf16)t[tx][ty + i * 8];
    }
}

// ---------------- fused QKV GEMM, z-merged + XCD-swizzled + BK=64 ----------------
// Grid (64 m-tiles, 24 n-tiles over 3072 cols). id = bx + 64*by -> id%8 = bx%8:
// all n-tiles of one m-tile run on the SAME XCD -> A-tile HBM-fetched once.
// NOTE R6 lesson: NO min-waves launch bound — forcing 4 waves/SIMD on a
// ~120-VGPR kernel spilled acc to scratch (WRITE_SIZE 49MB->1.4GB, 5x slower).
__global__ __launch_bounds__(256) void k_gemm_qkv(const bf16* __restrict__ xb,
                                                  const bf16* __restrict__ wt,
                                                  const float* __restrict__ bq,
                                                  const float* __restrict__ bk,
                                                  const float* __restrict__ bv,
                                                  bf16* __restrict__ qkv,
                                                  bf16* __restrict__ vtg) {
    __shared__ bf16 As[2 * 128 * 32];   // 16 KB: two 32-wide k-panels
    __shared__ bf16 Bs[2 * 128 * 32];   // 16 KB

    int tid = threadIdx.x;
    int lane = tid & 63, wid = tid >> 6;
    int ln = lane & 15, qd = lane >> 4;
    int wm = wid >> 1, wn = wid & 1;
    int m0 = blockIdx.x * 128;                 // m-tile (x-fastest -> XCD pin)
    int n0 = blockIdx.y * 128;                 // global col in [0,3072)
    int z = n0 >> 10;
    const float* bias = (z == 0) ? bq : (z == 1) ? bk : bv;
    float scale = (z == 0) ? 0.125f * 1.44269504088896f : 1.0f;  // 1/sqrt(Dk)*log2e folded into Q
    bool swapped = (z < 2);

    f32x4 zero4 = {0.f, 0.f, 0.f, 0.f};
    f32x4 acc[4][4];
#pragma unroll
    for (int i = 0; i < 4; i++)
#pragma unroll
        for (int j = 0; j < 4; j++) acc[i][j] = zero4;

    for (int k0 = 0; k0 < D_MODEL; k0 += 64) {
#pragma unroll
        for (int t = 0; t < 4; t++) {
            int c = t * 256 + tid;             // 0..1023, 16B each
            int ch = c >> 9, w = c & 511;      // panel, slot
            int row = w >> 2, part = w & 3;
            async_ld16(xb + (size_t)(m0 + row) * D_MODEL + k0 + ch * 32 + part * 8,
                       As + ch * 4096 + (w & ~63) * 8);
            async_ld16(wt + (size_t)(n0 + row) * D_MODEL + k0 + ch * 32 + part * 8,
                       Bs + ch * 4096 + (w & ~63) * 8);
        }
        __syncthreads();
#pragma unroll
        for (int kc = 0; kc < 2; kc++) {
            bf16x8 af[4], bfr[4];
#pragma unroll
            for (int mi = 0; mi < 4; mi++)
                af[mi] = *(const bf16x8*)(As + kc * 4096 + (wm * 64 + mi * 16 + ln) * 32 + qd * 8);
#pragma unroll
            for (int ni = 0; ni < 4; ni++)
                bfr[ni] = *(const bf16x8*)(Bs + kc * 4096 + (wn * 64 + ni * 16 + ln) * 32 + qd * 8);
            if (swapped) {
#pragma unroll
                for (int mi = 0; mi < 4; mi++)
#pragma unroll
                    for (int ni = 0; ni < 4; ni++)
                        acc[mi][ni] = __builtin_amdgcn_mfma_f32_16x16x32_bf16(bfr[ni], af[mi],
                                                                              acc[mi][ni], 0, 0, 0);
            } else {
#pragma unroll
                for (int mi = 0; mi < 4; mi++)
#pragma unroll
                    for (int ni = 0; ni < 4; ni++)
                        acc[mi][ni] = __builtin_amdgcn_mfma_f32_16x16x32_bf16(af[mi], bfr[ni],
                                                                              acc[mi][ni], 0, 0, 0);
            }
        }
        __syncthreads();
    }

    if (swapped) {
        // D[n][m]: lane holds x-row s (fixed), 4 consecutive W-cols (d)
        bf16* out = qkv + (size_t)z * M_TOT * D_MODEL;
#pragma unroll
        for (int mi = 0; mi < 4; mi++) {
            int srow = m0 + wm * 64 + mi * 16 + ln;
            int b = srow >> 11, s = srow & 2047;
#pragma unroll
            for (int ni = 0; ni < 4; ni++) {
                int colz = (n0 & 1023) + wn * 64 + ni * 16 + qd * 4;
                f32x4 bb = *(const f32x4*)(bias + colz);
                int h = colz >> 6, d = colz & 63;
                bf16x4 p;
#pragma unroll
                for (int r = 0; r < 4; r++)
                    p[r] = (bf16)((acc[mi][ni][r] + bb[r]) * scale);
                *(bf16x4*)(out + (((size_t)(b * NHEAD + h)) * SEQ + s) * DKH + d) = p;
            }
        }
    } else {
        // D[m][n]: lane holds W-col d (fixed), 4 consecutive x-rows (s) -> V^T direct
#pragma unroll
        for (int ni = 0; ni < 4; ni++) {
            int colz = (n0 & 1023) + wn * 64 + ni * 16 + ln;
            float bcol = bias[colz];
            int h = colz >> 6, d = colz & 63;
#pragma unroll
            for (int mi = 0; mi < 4; mi++) {
                int rb = m0 + wm * 64 + mi * 16 + qd * 4;
                int b = rb >> 11, s = rb & 2047;
                bf16x4 p;
#pragma unroll
                for (int r = 0; r < 4; r++)
                    p[r] = (bf16)(acc[mi][ni][r] + bcol);
                *(bf16x4*)(vtg + (((size_t)(b * NHEAD + h)) * DKH + d) * SEQ + s) = p;
            }
        }
    }
}

// ---------------- flash attention v6: 32x32 MFMA, in-register P ----------------
// R9 rewrite per m214/T12 structure:
//  * scores S^T = K·Q^T at 32x32x16: C col = q = lane&31 -> lanes l,l+32 are
//    partners on the SAME q-row holding complementary key halves.
//  * P stays in registers: exp2 -> pack bf16 pairs -> 2x v_permlane32_swap per
//    16-key PV step builds the B-fragment directly (no Ps LDS, no bank conflicts).
//  * row-sum l: lane-local adds folded into exp loop (all 32 values in a lane
//    share one q) + one __shfl_xor(32) at the end. Deletes the 4 ones-MFMAs/iter.
//  * K/V in [64][64] LDS, XOR chunk swizzle ch ^= (row^row>>3)&7 applied on the
//    global SOURCE of global_load_lds (linear dest) and on the ds_read address
//    (rule 21) -> conflict-free b128 A-frag reads.
//  * 2-phase double buffer (T3-min): stage next tile, compute, single
//    s_waitcnt vmcnt(0) + raw s_barrier per tile -> staging overlaps MFMA.
__global__ __launch_bounds__(256, 3) void k_attn(const bf16* __restrict__ qg,
                                                 const bf16* __restrict__ kg,
                                                 const bf16* __restrict__ vtg,
                                                 bf16* __restrict__ og) {
    __shared__ bf16 Ks[2 * 64 * 64];        // 16 KB (2 buffers)
    __shared__ bf16 Vs[2 * 64 * 64];        // 16 KB

    int tid = threadIdx.x;
    int lane = tid & 63, wid = tid >> 6;
    int ln32 = lane & 31, hi = lane >> 5;
    int bh = blockIdx.x;                    // x-fastest -> XCD pin per head
    int q0 = blockIdx.y * 128;
    int b = bh >> 4, h = bh & 15;

    const bf16* qp = qg + (size_t)bh * SEQ * DKH;
    const bf16* kp = kg + (size_t)bh * SEQ * DKH;
    const bf16* vp = vtg + (size_t)bh * DKH * SEQ;

    // stage one 64-key tile: K rows = keys, V rows = d. 512 chunks of 16B each.
    // LDS is linear (global_load_lds constraint); source chunk pre-swizzled.
    auto STAGE = [&](int bb, int kt) {
#pragma unroll
        for (int t = 0; t < 2; t++) {
            int c = t * 256 + tid;              // 0..511
            int row = c >> 3, chl = c & 7;
            int chg = chl ^ ((row ^ (row >> 3)) & 7);
            async_ld16(kp + (size_t)(kt + row) * DKH + chg * 8,
                       Ks + bb * 4096 + (c & ~63) * 8);
            async_ld16(vp + (size_t)row * SEQ + kt + chg * 8,
                       Vs + bb * 4096 + (c & ~63) * 8);
        }
    };

    STAGE(0, 0);

    // Q^T B-fragments (pre-scaled by log2e/8 in QKV GEMM): lane -> col q, k = kk*16+hi*8
    bf16x8 qa[4];
#pragma unroll
    for (int kk = 0; kk < 4; kk++)
        qa[kk] = *(const bf16x8*)(qp + (size_t)(q0 + wid * 32 + ln32) * DKH + kk * 16 + hi * 8);

    f32x16 o_acc[2];                         // O^T[d][q], d-blocks of 32
#pragma unroll
    for (int db = 0; db < 2; db++)
#pragma unroll
        for (int r = 0; r < 16; r++) o_acc[db][r] = 0.f;
    f32x4 lsum4 = {0.f, 0.f, 0.f, 0.f};

    asm volatile("s_waitcnt vmcnt(0)" ::: "memory");
    __builtin_amdgcn_s_barrier();

    for (int t = 0; t < 32; t++) {
        int bb = t & 1;
        if (t < 31) STAGE(bb ^ 1, (t + 1) * 64);

        // S^T = K·Q^T (log2 domain): two independent 32-key chains for ILP
        f32x16 sc[2];
#pragma unroll
        for (int kb = 0; kb < 2; kb++)
#pragma unroll
            for (int r = 0; r < 16; r++) sc[kb][r] = 0.f;
#pragma unroll
        for (int kk = 0; kk < 4; kk++) {
#pragma unroll
            for (int kb = 0; kb < 2; kb++) {
                int kr = kb * 32 + ln32;
                bf16x8 kf = *(const bf16x8*)(Ks + bb * 4096 + kr * 64
                                + (size_t)(((2 * kk + hi) ^ ((kr ^ (kr >> 3)) & 7)) * 8));
                sc[kb] = __builtin_amdgcn_mfma_f32_32x32x16_bf16(kf, qa[kk], sc[kb], 0, 0, 0);
            }
        }

        // per 32-key block: exp2 -> pack -> permlane swaps -> PV
#pragma unroll
        for (int kb = 0; kb < 2; kb++) {
            float e[16];
#pragma unroll
            for (int r = 0; r < 16; r++) e[r] = __builtin_amdgcn_exp2f(sc[kb][r]);
#pragma unroll
            for (int r = 0; r < 16; r++) lsum4[r & 3] += e[r];
            unsigned pd[8];   // pd[j] = bf16 pair of keys crow(2j),crow(2j+1)
#pragma unroll
            for (int j = 0; j < 8; j++) pd[j] = pack2_bf16(e[2 * j], e[2 * j + 1]);
#pragma unroll
            for (int ks = 0; ks < 2; ks++) {
                // swap(dst,src): dst.upper <-> src.lower; partners share q.
                unsigned a0 = pd[ks * 4 + 0], b0 = pd[ks * 4 + 2];
                unsigned a1 = pd[ks * 4 + 1], b1 = pd[ks * 4 + 3];
                asm volatile("v_permlane32_swap_b32 %0, %1" : "+v"(a0), "+v"(b0));
                asm volatile("v_permlane32_swap_b32 %0, %1" : "+v"(a1), "+v"(b1));
                union { unsigned u[4]; bf16x8 v; } pf;
                pf.u[0] = a0; pf.u[1] = a1; pf.u[2] = b0; pf.u[3] = b1;
#pragma unroll
                for (int db = 0; db < 2; db++) {
                    int vr = db * 32 + ln32;
                    bf16x8 vf = *(const bf16x8*)(Vs + bb * 4096 + vr * 64
                                    + (size_t)(((4 * kb + 2 * ks + hi) ^ ((vr ^ (vr >> 3)) & 7)) * 8));
                    o_acc[db] = __builtin_amdgcn_mfma_f32_32x32x16_bf16(vf, pf.v, o_acc[db], 0, 0, 0);
                }
            }
        }

        if (t < 31) {
            asm volatile("s_waitcnt vmcnt(0)" ::: "memory");
            __builtin_amdgcn_s_barrier();
        }
    }

    // l = sum over all 64 keys/iter: this lane's 32 + partner's 32
    float lsum = (lsum4[0] + lsum4[1]) + (lsum4[2] + lsum4[3]);
    float lt = lsum + __shfl_xor(lsum, 32, 64);
    float inv = 1.0f / lt;

    // O^T: reg r of o_acc[db] = O[d = (r&3)+8*(r>>2)+4*hi+32*db][q = ln32]
    int s = q0 + wid * 32 + ln32;
    size_t rowoff = ((size_t)b * SEQ + s) * D_MODEL + h * DKH;
#pragma unroll
    for (int db = 0; db < 2; db++)
#pragma unroll
        for (int q4 = 0; q4 < 4; q4++) {
            bf16x4 pv4;
#pragma unroll
            for (int j = 0; j < 4; j++) pv4[j] = (bf16)(o_acc[db][q4 * 4 + j] * inv);
            *(bf16x4*)(og + rowoff + db * 32 + q4 * 8 + hi * 4) = pv4;
        }
}

// ---------------- output GEMM: O[8192x1024] @ Wo + bo -> fp32 ----------------
// BK=64 + XCD-swizzled grid (x=m, y=n). Transposed epilogue, float4 stores.
__global__ __launch_bounds__(256) void k_gemm_out(const bf16* __restrict__ ob,
                                                  const bf16* __restrict__ wot,
                                                  const float* __restrict__ bo,
                                                  float* __restrict__ out) {
    __shared__ bf16 As[2 * 128 * 32];
    __shared__ bf16 Bs[2 * 128 * 32];

    int tid = threadIdx.x;
    int lane = tid & 63, wid = tid >> 6;
    int ln = lane & 15, qd = lane >> 4;
    int wm = wid >> 1, wn = wid & 1;
    int m0 = blockIdx.x * 128, n0 = blockIdx.y * 128;

    f32x4 zero4 = {0.f, 0.f, 0.f, 0.f};
    f32x4 acc[4][4];
#pragma unroll
    for (int i = 0; i < 4; i++)
#pragma unroll
        for (int j = 0; j < 4; j++) acc[i][j] = zero4;

    for (int k0 = 0; k0 < D_MODEL; k0 += 64) {
#pragma unroll
        for (int t = 0; t < 4; t++) {
            int c = t * 256 + tid;
            int ch = c >> 9, w = c & 511;
            int row = w >> 2, part = w & 3;
            async_ld16(ob + (size_t)(m0 + row) * D_MODEL + k0 + ch * 32 + part * 8,
                       As + ch * 4096 + (w & ~63) * 8);
            async_ld16(wot + (size_t)(n0 + row) * D_MODEL + k0 + ch * 32 + part * 8,
                       Bs + ch * 4096 + (w & ~63) * 8);
        }
        __syncthreads();
#pragma unroll
        for (int kc = 0; kc < 2; kc++) {
            bf16x8 af[4], bfr[4];
#pragma unroll
            for (int mi = 0; mi < 4; mi++)
                af[mi] = *(const bf16x8*)(As + kc * 4096 + (wm * 64 + mi * 16 + ln) * 32 + qd * 8);
#pragma unroll
            for (int ni = 0; ni < 4; ni++)
                bfr[ni] = *(const bf16x8*)(Bs + kc * 4096 + (wn * 64 + ni * 16 + ln) * 32 + qd * 8);
#pragma unroll
            for (int mi = 0; mi < 4; mi++)
#pragma unroll
                for (int ni = 0; ni < 4; ni++)
                    acc[mi][ni] = __builtin_amdgcn_mfma_f32_16x16x32_bf16(bfr[ni], af[mi],
                                                                          acc[mi][ni], 0, 0, 0);
        }
        __syncthreads();
    }

#pragma unroll
    for (int mi = 0; mi < 4; mi++) {
        int row = m0 + wm * 64 + mi * 16 + ln;
#pragma unroll
        for (int ni = 0; ni < 4; ni++) {
            int col4 = n0 + wn * 64 + ni * 16 + qd * 4;
            f32x4 bb = *(const f32x4*)(bo + col4);
            f32x4 v;
#pragma unroll
            for (int r = 0; r < 4; r++) v[r] = acc[mi][ni][r] + bb[r];
            *(f32x4*)(out + (size_t)row * D_MODEL + col4) = v;
        }
    }
}

extern "C" void kernel_launch(void* const* d_in, const int* in_sizes, int n_in,
                              void* d_out, int out_size, void* d_ws, size_t ws_size,
                              hipStream_t stream) {
    const float* x  = (const float*)d_in[0];
    const float* wq = (const float*)d_in[1];
    const float* bq = (const float*)d_in[2];
    const float* wk = (const float*)d_in[3];
    const float* bk = (const float*)d_in[4];
    const float* wv = (const float*)d_in[5];
    const float* bv = (const float*)d_in[6];
    const float* wo = (const float*)d_in[7];
    const float* bo = (const float*)d_in[8];
    float* out = (float*)d_out;

    char* ws = (char*)d_ws;
    bf16* xb  = (bf16*)ws;                    // 16.8 MB (reused as og after QKV GEMM)
    bf16* wt  = (bf16*)(ws + 16777216);       //  8.4 MB (wq,wk,wv,wo transposed, contiguous)
    bf16* qkv = (bf16*)(ws + 25165824);       // Q,K
    bf16* vtg = (bf16*)(ws + 75497472);       // V^T written directly by GEMM
    bf16* og  = xb;

    k_cvt<<<dim3(8192 + 4096), dim3(256), 0, stream>>>(x, xb, wq, wk, wv, wo, wt);
    k_gemm_qkv<<<dim3(64, 24), dim3(256), 0, stream>>>(xb, wt, bq, bk, bv, qkv, vtg);
    k_attn<<<dim3(64, 16), dim3(256), 0, stream>>>(qkv, qkv + (size_t)M_TOT * D_MODEL, vtg, og);
    k_gemm_out<<<dim3(64, 8), dim3(256), 0, stream>>>(og, wt + 3 * (size_t)D_MODEL * D_MODEL,
                                                      bo, out);
}